// Round 6
// baseline (157.695 us; speedup 1.0000x reference)
//
#include <hip/hip_runtime.h>

typedef _Float16 h16;
typedef _Float16 h16x4 __attribute__((ext_vector_type(4)));
typedef _Float16 h16x8 __attribute__((ext_vector_type(8)));
typedef __fp16 fp16x2 __attribute__((ext_vector_type(2)));   // cvt_pkrtz native type
typedef float f32x4 __attribute__((ext_vector_type(4)));

#define SEQ 2048
#define RSTRIDE 8192   // b*h*d = 4*16*128
#define QTILE 128
#define NQT (SEQ / QTILE)   // 16
#define KBLK 64
#define KPAD 136       // K LDS row stride (halves)
#define VPAD 72        // Vt LDS row stride (halves)
#define DEFER_THR 8.0f

// pack 8 f32 -> 8 f16 via v_cvt_pkrtz (4 instrs instead of ~12)
static __device__ __forceinline__ h16x8 pack8(f32x4 a, f32x4 b) {
    union { fp16x2 h2[4]; h16x8 h8; } u;
    u.h2[0] = __builtin_amdgcn_cvt_pkrtz(a[0], a[1]);
    u.h2[1] = __builtin_amdgcn_cvt_pkrtz(a[2], a[3]);
    u.h2[2] = __builtin_amdgcn_cvt_pkrtz(b[0], b[1]);
    u.h2[3] = __builtin_amdgcn_cvt_pkrtz(b[2], b[3]);
    return u.h8;
}

static __device__ __forceinline__ h16x4 pack4(float x0, float x1, float x2, float x3) {
    union { fp16x2 h2[2]; h16x4 h4; } u;
    u.h2[0] = __builtin_amdgcn_cvt_pkrtz(x0, x1);
    u.h2[1] = __builtin_amdgcn_cvt_pkrtz(x2, x3);
    return u.h4;
}

__global__ __launch_bounds__(512, 2)
void fa_fwd_kernel(const float* __restrict__ Qg, const float* __restrict__ Kg,
                   const float* __restrict__ Vg, float* __restrict__ Out)
{
    __shared__ __attribute__((aligned(16))) h16 Kl[2][KBLK * KPAD];   // [key][d]
    __shared__ __attribute__((aligned(16))) h16 Vt[2][128 * VPAD];    // [d][key^swz]

    // XCD-aware remap: each XCD gets 8 contiguous bh (K/V locality in its L2)
    const int lin = (int)blockIdx.x + 8 * (int)blockIdx.y;   // 0..511
    const int xsw = (lin & 7) * 64 + (lin >> 3);             // bijective
    const int bx  = xsw & 7;        // 0..7, pairs (bx, 15-bx)
    const int bh  = xsw >> 3;       // 0..63
    const int tid  = threadIdx.x;   // 0..511 (8 waves)
    const int wave = tid >> 6;
    const int lane = tid & 63;
    const int lg   = lane >> 4;
    const int lc   = lane & 15;
    const size_t bhoff = (size_t)bh * 128;
    const float NEGINF = -__builtin_inff();
    const float SL = 0.08838834764831845f * 1.4426950408889634f;  // (1/sqrt(128))*log2(e)

    // ---- K staging geometry: 2 iters x (row = tid>>4 + 32*it, 8 floats)
    const int krow = tid >> 4;            // 0..31
    const int kd0  = (tid & 15) * 8;
    const float* kbase = Kg + (size_t)krow * RSTRIDE + bhoff + kd0;
    const int kwoff = krow * KPAD + kd0;

    // ---- V staging geometry: thread owns 4 keys x 4 d's, one pass
    const int vkey0 = 4 * (tid >> 5);     // 0..60
    const int vd0   = 4 * (tid & 31);     // 0..124
    const int vcol  = vkey0 ^ (4 * (tid & 15));   // swz(d)=4*((d>>2)&15) == 4*(tid&15)
    const float* vbase = Vg + (size_t)vkey0 * RSTRIDE + bhoff + vd0;

    // ---- per-lane LDS fragment bases (swizzle algebra folded; rest is immediates)
    const int kfoff = lc * KPAD + lg * 8;                      // + kt*16*KPAD + dk*32
    const int vfoff = lc * VPAD + ((4 * lg) ^ (4 * (lc >> 2)));// + dt*16*VPAD + 16*((2u+s)^(dt&3))

    f32x4 kra[2], krb[2], vra[4];   // prefetch registers (T14)

    for (int half = 0; half < 2; ++half) {
        const int qt = half ? (NQT - 1 - bx) : bx;
        const int q0 = qt * QTILE;
        const int qsbase = q0 + wave * 16;   // this wave's 16 q-rows

        // ---- Q fragments, pre-scaled by scale*log2e: qf[dk][j] = SL*Q[qrow][32dk+8lg+j]
        h16x8 qf[4];
        {
            const int qrow = qsbase + lc;
            const float* qp = Qg + (size_t)qrow * RSTRIDE + bhoff + lg * 8;
#pragma unroll
            for (int dk = 0; dk < 4; ++dk) {
                f32x4 a = *(const f32x4*)(qp + dk * 32);
                f32x4 b = *(const f32x4*)(qp + dk * 32 + 4);
#pragma unroll
                for (int j = 0; j < 4; ++j) { a[j] *= SL; b[j] *= SL; }
                qf[dk] = pack8(a, b);
            }
        }

        f32x4 o[8];
#pragma unroll
        for (int dt = 0; dt < 8; ++dt) o[dt] = f32x4{0.f, 0.f, 0.f, 0.f};
        float mreg = NEGINF;
        float lsum = 0.f;   // lane-partial; reduced across lane-groups in epilogue

        const int nkv = 2 * (qt + 1);

        // ---- prologue: load t0 -> regs, write buf0, load t1 -> regs, barrier
#pragma unroll
        for (int it = 0; it < 2; ++it) {
            const float* gp = kbase + (size_t)(32 * it) * RSTRIDE;
            kra[it] = *(const f32x4*)gp;
            krb[it] = *(const f32x4*)(gp + 4);
        }
#pragma unroll
        for (int kk = 0; kk < 4; ++kk)
            vra[kk] = *(const f32x4*)(vbase + (size_t)kk * RSTRIDE);
        __syncthreads();   // previous half's compute fully done before overwrite
        {
            h16* kw = &Kl[0][kwoff];
#pragma unroll
            for (int it = 0; it < 2; ++it)
                *(h16x8*)(kw + it * 32 * KPAD) = pack8(kra[it], krb[it]);
#pragma unroll
            for (int e = 0; e < 4; ++e)
                *(h16x4*)&Vt[0][(vd0 + e) * VPAD + vcol] =
                    pack4(vra[0][e], vra[1][e], vra[2][e], vra[3][e]);
        }
        if (nkv > 1) {
            const size_t toff = (size_t)KBLK * RSTRIDE;
#pragma unroll
            for (int it = 0; it < 2; ++it) {
                const float* gp = kbase + toff + (size_t)(32 * it) * RSTRIDE;
                kra[it] = *(const f32x4*)gp;
                krb[it] = *(const f32x4*)(gp + 4);
            }
#pragma unroll
            for (int kk = 0; kk < 4; ++kk)
                vra[kk] = *(const f32x4*)(vbase + toff + (size_t)kk * RSTRIDE);
        }
        __syncthreads();   // buf0 visible

        for (int t = 0; t < nkv; ++t) {
            const int kv0 = t * KBLK;
            const int cb = t & 1;

            // ---- write staged regs (tile t+1) -> other buffer (overlaps compute below)
            if (t + 1 < nkv) {
                h16* kw = &Kl[cb ^ 1][kwoff];
#pragma unroll
                for (int it = 0; it < 2; ++it)
                    *(h16x8*)(kw + it * 32 * KPAD) = pack8(kra[it], krb[it]);
#pragma unroll
                for (int e = 0; e < 4; ++e)
                    *(h16x4*)&Vt[cb ^ 1][(vd0 + e) * VPAD + vcol] =
                        pack4(vra[0][e], vra[1][e], vra[2][e], vra[3][e]);
            }
            // ---- issue tile t+2 global loads (land during compute of t, t+1)
            if (t + 2 < nkv) {
                const size_t toff = (size_t)(kv0 + 2 * KBLK) * RSTRIDE;
#pragma unroll
                for (int it = 0; it < 2; ++it) {
                    const float* gp = kbase + toff + (size_t)(32 * it) * RSTRIDE;
                    kra[it] = *(const f32x4*)gp;
                    krb[it] = *(const f32x4*)(gp + 4);
                }
#pragma unroll
                for (int kk = 0; kk < 4; ++kk)
                    vra[kk] = *(const f32x4*)(vbase + toff + (size_t)kk * RSTRIDE);
            }

            // ---- compute: one 16-row strip per wave
            if (kv0 <= qsbase + 15) {          // wave-uniform skip
                const h16* Kfb = &Kl[cb][kfoff];
                const h16* Vfb = &Vt[cb][vfoff];

                // S^T = K . Q^T : sacc[kt] holds keys kv0+16kt+4lg+r, q col = lc
                f32x4 sacc[4];
#pragma unroll
                for (int kt = 0; kt < 4; ++kt) sacc[kt] = f32x4{0.f, 0.f, 0.f, 0.f};
                __builtin_amdgcn_s_setprio(1);
#pragma unroll
                for (int kt = 0; kt < 4; ++kt) {
#pragma unroll
                    for (int dk = 0; dk < 4; ++dk) {
                        h16x8 a = *(const h16x8*)(Kfb + kt * 16 * KPAD + dk * 32);
                        sacc[kt] = __builtin_amdgcn_mfma_f32_16x16x32_f16(a, qf[dk], sacc[kt], 0, 0, 0);
                    }
                }
                __builtin_amdgcn_s_setprio(0);

                // per-lane max (mask only on non-interior tiles; wave-uniform branch)
                float vmax = NEGINF;
                if (kv0 + 63 <= qsbase) {
#pragma unroll
                    for (int kt = 0; kt < 4; ++kt)
#pragma unroll
                        for (int r = 0; r < 4; ++r) vmax = fmaxf(vmax, sacc[kt][r]);
                } else {
                    const int qrow = qsbase + lc;
#pragma unroll
                    for (int kt = 0; kt < 4; ++kt)
#pragma unroll
                        for (int r = 0; r < 4; ++r) {
                            const int key = kv0 + 16 * kt + 4 * lg + r;
                            float sv = (key <= qrow) ? sacc[kt][r] : NEGINF;
                            sacc[kt][r] = sv;
                            vmax = fmaxf(vmax, sv);
                        }
                }

                // T13 defer-max: full rescale only when some row grew past threshold
                if (__any(vmax > mreg + DEFER_THR)) {
                    float rmax = fmaxf(vmax, __shfl_xor(vmax, 16, 64));
                    rmax = fmaxf(rmax, __shfl_xor(rmax, 32, 64));
                    const float mnew  = fmaxf(mreg, rmax);
                    const float alpha = __builtin_exp2f(mreg - mnew);
                    mreg = mnew;
                    lsum *= alpha;      // lane-partial, row-uniform alpha distributes
#pragma unroll
                    for (int r = 0; r < 4; ++r) {
                        const float ar = __shfl(alpha, 4 * lg + r, 64);
#pragma unroll
                        for (int dt = 0; dt < 8; ++dt) o[dt][r] *= ar;
                    }
                }

                // P = exp2(S - m), lane-partial row sum (bounded by 2^THR)
                float psum = 0.f;
#pragma unroll
                for (int kt = 0; kt < 4; ++kt)
#pragma unroll
                    for (int r = 0; r < 4; ++r) {
                        const float e = __builtin_exp2f(sacc[kt][r] - mreg);
                        sacc[kt][r] = e;
                        psum += e;
                    }
                lsum += psum;

                // P fragments (in-lane via k-slot bijection: key = 32u+4g+(j&3)+16(j>>2))
                h16x8 pa[2];
#pragma unroll
                for (int u = 0; u < 2; ++u) pa[u] = pack8(sacc[2 * u], sacc[2 * u + 1]);

                // PV: all 16 ds_read addresses = per-lane base + compile-time immediates
                __builtin_amdgcn_s_setprio(1);
#pragma unroll
                for (int dt = 0; dt < 8; ++dt) {
#pragma unroll
                    for (int u = 0; u < 2; ++u) {
                        union { h16x8 v8; h16x4 v4[2]; } bv;
                        bv.v4[0] = *(const h16x4*)(Vfb + dt * 16 * VPAD + 16 * ((2 * u + 0) ^ (dt & 3)));
                        bv.v4[1] = *(const h16x4*)(Vfb + dt * 16 * VPAD + 16 * ((2 * u + 1) ^ (dt & 3)));
                        o[dt] = __builtin_amdgcn_mfma_f32_16x16x32_f16(pa[u], bv.v8, o[dt], 0, 0, 0);
                    }
                }
                __builtin_amdgcn_s_setprio(0);
            }
            __syncthreads();   // single barrier per tile: buf (t+1) written, buf t consumed
        } // kv tiles

        // ---- epilogue: reduce lane-partial lsum across lane-groups, normalize, store
        lsum += __shfl_xor(lsum, 16, 64);
        lsum += __shfl_xor(lsum, 32, 64);
#pragma unroll
        for (int r = 0; r < 4; ++r) {
            const float lr  = __shfl(lsum, 4 * lg + r, 64);
            const float inv = 1.0f / lr;
            const int qrow  = qsbase + 4 * lg + r;
            float* op = Out + (size_t)qrow * RSTRIDE + bhoff + lc;
#pragma unroll
            for (int dt = 0; dt < 8; ++dt) op[dt * 16] = o[dt][r] * inv;
        }
    } // half
}

extern "C" void kernel_launch(void* const* d_in, const int* in_sizes, int n_in,
                              void* d_out, int out_size, void* d_ws, size_t ws_size,
                              hipStream_t stream) {
    (void)in_sizes; (void)n_in; (void)out_size; (void)d_ws; (void)ws_size;
    const float* Q = (const float*)d_in[0];
    const float* K = (const float*)d_in[1];
    const float* V = (const float*)d_in[2];
    float* O = (float*)d_out;
    dim3 grid(NQT / 2, 64);
    fa_fwd_kernel<<<grid, 512, 0, stream>>>(Q, K, V, O);
}

// Round 7
// 135.204 us; speedup vs baseline: 1.1663x; 1.1663x over previous
//
#include <hip/hip_runtime.h>

typedef _Float16 h16;
typedef _Float16 h16x4 __attribute__((ext_vector_type(4)));
typedef _Float16 h16x8 __attribute__((ext_vector_type(8)));
typedef __fp16 fp16x2 __attribute__((ext_vector_type(2)));   // cvt_pkrtz native type
typedef float f32x4 __attribute__((ext_vector_type(4)));

#define SEQ 2048
#define RSTRIDE 8192   // b*h*d = 4*16*128
#define QTILE 256
#define NQT (SEQ / QTILE)   // 8
#define KBLK 64
#define KPAD 136       // K LDS row stride (halves)
#define VPAD 72        // Vt LDS row stride (halves)
#define DEFER_THR 8.0f

// pack 8 f32 -> 8 f16 via v_cvt_pkrtz
static __device__ __forceinline__ h16x8 pack8(f32x4 a, f32x4 b) {
    union { fp16x2 h2[4]; h16x8 h8; } u;
    u.h2[0] = __builtin_amdgcn_cvt_pkrtz(a[0], a[1]);
    u.h2[1] = __builtin_amdgcn_cvt_pkrtz(a[2], a[3]);
    u.h2[2] = __builtin_amdgcn_cvt_pkrtz(b[0], b[1]);
    u.h2[3] = __builtin_amdgcn_cvt_pkrtz(b[2], b[3]);
    return u.h8;
}

static __device__ __forceinline__ h16x4 pack4(float x0, float x1, float x2, float x3) {
    union { fp16x2 h2[2]; h16x4 h4; } u;
    u.h2[0] = __builtin_amdgcn_cvt_pkrtz(x0, x1);
    u.h2[1] = __builtin_amdgcn_cvt_pkrtz(x2, x3);
    return u.h4;
}

__global__ __launch_bounds__(512, 2)
void fa_fwd_kernel(const float* __restrict__ Qg, const float* __restrict__ Kg,
                   const float* __restrict__ Vg, float* __restrict__ Out)
{
    __shared__ __attribute__((aligned(16))) h16 Kl[2][KBLK * KPAD];   // [key][d]
    __shared__ __attribute__((aligned(16))) h16 Vt[2][128 * VPAD];    // [d][key^swz]

    // XCD-aware remap (256 blocks, 1/CU): XCD x owns bh in {8x..8x+7}
    const int lin = (int)blockIdx.x + 4 * (int)blockIdx.y;   // hw XCD = lin % 8
    const int bx  = (lin >> 3) & 3;          // 0..3, pairs (bx, 7-bx)
    const int bh  = 8 * (lin & 7) + (lin >> 5);   // 0..63
    const int tid  = threadIdx.x;   // 0..511 (8 waves)
    const int wave = tid >> 6;
    const int lane = tid & 63;
    const int lg   = lane >> 4;
    const int lc   = lane & 15;
    const size_t bhoff = (size_t)bh * 128;
    const float NEGINF = -__builtin_inff();
    const float SL = 0.08838834764831845f * 1.4426950408889634f;  // (1/sqrt(128))*log2(e)

    // ---- K staging geometry: 2 iters x (row = tid>>4 + 32*it, 8 floats)
    const int krow = tid >> 4;            // 0..31
    const int kd0  = (tid & 15) * 8;
    const float* kbase = Kg + (size_t)krow * RSTRIDE + bhoff + kd0;
    const int kwoff = krow * KPAD + kd0;

    // ---- V staging geometry: thread owns 4 keys x 4 d's, one pass
    const int vkey0 = 4 * (tid >> 5);     // 0..60
    const int vd0   = 4 * (tid & 31);     // 0..124
    const int vcol  = vkey0 ^ (4 * (tid & 15));   // swz(d)=4*((d>>2)&15) == 4*(tid&15)
    const float* vbase = Vg + (size_t)vkey0 * RSTRIDE + bhoff + vd0;

    // ---- per-lane LDS fragment bases
    const int kfoff = lc * KPAD + lg * 8;                      // + kt*16*KPAD + dk*32
    const int vfoff = lc * VPAD + ((4 * lg) ^ (4 * (lc >> 2)));// + dt*16*VPAD + 16*((2u+s)^(dt&3))

    f32x4 kra[2], krb[2], vra[4];   // prefetch registers (T14)

    for (int half = 0; half < 2; ++half) {
        const int qt = half ? (NQT - 1 - bx) : bx;
        const int q0 = qt * QTILE;
        const int wbase = q0 + wave * 32;    // this wave's 32 q-rows (2 strips of 16)

        // ---- Q fragments, pre-scaled: qf[s2][dk][j] = SL*Q[qrow][32dk+8lg+j]
        h16x8 qf[2][4];
#pragma unroll
        for (int s2 = 0; s2 < 2; ++s2) {
            const int qrow = wbase + s2 * 16 + lc;
            const float* qp = Qg + (size_t)qrow * RSTRIDE + bhoff + lg * 8;
#pragma unroll
            for (int dk = 0; dk < 4; ++dk) {
                f32x4 a = *(const f32x4*)(qp + dk * 32);
                f32x4 b = *(const f32x4*)(qp + dk * 32 + 4);
#pragma unroll
                for (int j = 0; j < 4; ++j) { a[j] *= SL; b[j] *= SL; }
                qf[s2][dk] = pack8(a, b);
            }
        }

        f32x4 o[2][8];
#pragma unroll
        for (int s2 = 0; s2 < 2; ++s2)
#pragma unroll
            for (int dt = 0; dt < 8; ++dt) o[s2][dt] = f32x4{0.f, 0.f, 0.f, 0.f};
        float mreg[2] = {NEGINF, NEGINF};
        float lsum[2] = {0.f, 0.f};   // lane-partial

        const int nkv = 4 * (qt + 1);

        // ---- prologue: load t0 -> regs, write buf0, load t1 -> regs, barrier
#pragma unroll
        for (int it = 0; it < 2; ++it) {
            const float* gp = kbase + (size_t)(32 * it) * RSTRIDE;
            kra[it] = *(const f32x4*)gp;
            krb[it] = *(const f32x4*)(gp + 4);
        }
#pragma unroll
        for (int kk = 0; kk < 4; ++kk)
            vra[kk] = *(const f32x4*)(vbase + (size_t)kk * RSTRIDE);
        __syncthreads();   // previous half's compute fully done before overwrite
        {
            h16* kw = &Kl[0][kwoff];
#pragma unroll
            for (int it = 0; it < 2; ++it)
                *(h16x8*)(kw + it * 32 * KPAD) = pack8(kra[it], krb[it]);
#pragma unroll
            for (int e = 0; e < 4; ++e)
                *(h16x4*)&Vt[0][(vd0 + e) * VPAD + vcol] =
                    pack4(vra[0][e], vra[1][e], vra[2][e], vra[3][e]);
        }
        if (nkv > 1) {
            const size_t toff = (size_t)KBLK * RSTRIDE;
#pragma unroll
            for (int it = 0; it < 2; ++it) {
                const float* gp = kbase + toff + (size_t)(32 * it) * RSTRIDE;
                kra[it] = *(const f32x4*)gp;
                krb[it] = *(const f32x4*)(gp + 4);
            }
#pragma unroll
            for (int kk = 0; kk < 4; ++kk)
                vra[kk] = *(const f32x4*)(vbase + toff + (size_t)kk * RSTRIDE);
        }
        __syncthreads();   // buf0 visible

        for (int t = 0; t < nkv; ++t) {
            const int kv0 = t * KBLK;
            const int cb = t & 1;

            // ---- write staged regs (tile t+1) -> other buffer (overlaps compute)
            if (t + 1 < nkv) {
                h16* kw = &Kl[cb ^ 1][kwoff];
#pragma unroll
                for (int it = 0; it < 2; ++it)
                    *(h16x8*)(kw + it * 32 * KPAD) = pack8(kra[it], krb[it]);
#pragma unroll
                for (int e = 0; e < 4; ++e)
                    *(h16x4*)&Vt[cb ^ 1][(vd0 + e) * VPAD + vcol] =
                        pack4(vra[0][e], vra[1][e], vra[2][e], vra[3][e]);
            }
            // ---- issue tile t+2 global loads
            if (t + 2 < nkv) {
                const size_t toff = (size_t)(kv0 + 2 * KBLK) * RSTRIDE;
#pragma unroll
                for (int it = 0; it < 2; ++it) {
                    const float* gp = kbase + toff + (size_t)(32 * it) * RSTRIDE;
                    kra[it] = *(const f32x4*)gp;
                    krb[it] = *(const f32x4*)(gp + 4);
                }
#pragma unroll
                for (int kk = 0; kk < 4; ++kk)
                    vra[kk] = *(const f32x4*)(vbase + toff + (size_t)kk * RSTRIDE);
            }

            // ---- compute: 2 strips of 16 q-rows per wave
#pragma unroll
            for (int s2 = 0; s2 < 2; ++s2) {
                const int sbase = wbase + s2 * 16;
                if (kv0 > sbase + 15) continue;    // wave-uniform skip, no barrier inside
                const h16* Kfb = &Kl[cb][kfoff];
                const h16* Vfb = &Vt[cb][vfoff];

                // S^T = K . Q^T : sacc[kt] keys kv0+16kt+4lg+r, q col = lc
                f32x4 sacc[4];
#pragma unroll
                for (int kt = 0; kt < 4; ++kt) sacc[kt] = f32x4{0.f, 0.f, 0.f, 0.f};
                __builtin_amdgcn_s_setprio(1);
#pragma unroll
                for (int kt = 0; kt < 4; ++kt) {
#pragma unroll
                    for (int dk = 0; dk < 4; ++dk) {
                        h16x8 a = *(const h16x8*)(Kfb + kt * 16 * KPAD + dk * 32);
                        sacc[kt] = __builtin_amdgcn_mfma_f32_16x16x32_f16(a, qf[s2][dk], sacc[kt], 0, 0, 0);
                    }
                }
                __builtin_amdgcn_s_setprio(0);

                // per-lane max (mask only on non-interior tiles)
                float vmax = NEGINF;
                if (kv0 + 63 <= sbase) {
#pragma unroll
                    for (int kt = 0; kt < 4; ++kt)
#pragma unroll
                        for (int r = 0; r < 4; ++r) vmax = fmaxf(vmax, sacc[kt][r]);
                } else {
                    const int qrow = sbase + lc;
#pragma unroll
                    for (int kt = 0; kt < 4; ++kt)
#pragma unroll
                        for (int r = 0; r < 4; ++r) {
                            const int key = kv0 + 16 * kt + 4 * lg + r;
                            float sv = (key <= qrow) ? sacc[kt][r] : NEGINF;
                            sacc[kt][r] = sv;
                            vmax = fmaxf(vmax, sv);
                        }
                }

                // T13 defer-max
                if (__any(vmax > mreg[s2] + DEFER_THR)) {
                    float rmax = fmaxf(vmax, __shfl_xor(vmax, 16, 64));
                    rmax = fmaxf(rmax, __shfl_xor(rmax, 32, 64));
                    const float mnew  = fmaxf(mreg[s2], rmax);
                    const float alpha = __builtin_amdgcn_exp2f(mreg[s2] - mnew);
                    mreg[s2] = mnew;
                    lsum[s2] *= alpha;
#pragma unroll
                    for (int r = 0; r < 4; ++r) {
                        const float ar = __shfl(alpha, 4 * lg + r, 64);
#pragma unroll
                        for (int dt = 0; dt < 8; ++dt) o[s2][dt][r] *= ar;
                    }
                }

                // P = exp2(S - m), lane-partial row sum
                float psum = 0.f;
#pragma unroll
                for (int kt = 0; kt < 4; ++kt)
#pragma unroll
                    for (int r = 0; r < 4; ++r) {
                        const float e = __builtin_amdgcn_exp2f(sacc[kt][r] - mreg[s2]);
                        sacc[kt][r] = e;
                        psum += e;
                    }
                lsum[s2] += psum;

                // P fragments (in-lane k-slot bijection: key = 32u+4g+(j&3)+16(j>>2))
                h16x8 pa[2];
#pragma unroll
                for (int u = 0; u < 2; ++u) pa[u] = pack8(sacc[2 * u], sacc[2 * u + 1]);

                // PV: base + compile-time immediates
                __builtin_amdgcn_s_setprio(1);
#pragma unroll
                for (int dt = 0; dt < 8; ++dt) {
#pragma unroll
                    for (int u = 0; u < 2; ++u) {
                        union { h16x8 v8; h16x4 v4[2]; } bv;
                        bv.v4[0] = *(const h16x4*)(Vfb + dt * 16 * VPAD + 16 * ((2 * u + 0) ^ (dt & 3)));
                        bv.v4[1] = *(const h16x4*)(Vfb + dt * 16 * VPAD + 16 * ((2 * u + 1) ^ (dt & 3)));
                        o[s2][dt] = __builtin_amdgcn_mfma_f32_16x16x32_f16(pa[u], bv.v8, o[s2][dt], 0, 0, 0);
                    }
                }
                __builtin_amdgcn_s_setprio(0);
            } // strips
            __syncthreads();   // single barrier per tile
        } // kv tiles

        // ---- epilogue
#pragma unroll
        for (int s2 = 0; s2 < 2; ++s2) {
            float ls = lsum[s2];
            ls += __shfl_xor(ls, 16, 64);
            ls += __shfl_xor(ls, 32, 64);
#pragma unroll
            for (int r = 0; r < 4; ++r) {
                const float lr  = __shfl(ls, 4 * lg + r, 64);
                const float inv = 1.0f / lr;
                const int qrow  = wbase + s2 * 16 + 4 * lg + r;
                float* op = Out + (size_t)qrow * RSTRIDE + bhoff + lc;
#pragma unroll
                for (int dt = 0; dt < 8; ++dt) op[dt * 16] = o[s2][dt][r] * inv;
            }
        }
    } // half
}

extern "C" void kernel_launch(void* const* d_in, const int* in_sizes, int n_in,
                              void* d_out, int out_size, void* d_ws, size_t ws_size,
                              hipStream_t stream) {
    (void)in_sizes; (void)n_in; (void)out_size; (void)d_ws; (void)ws_size;
    const float* Q = (const float*)d_in[0];
    const float* K = (const float*)d_in[1];
    const float* V = (const float*)d_in[2];
    float* O = (float*)d_out;
    dim3 grid(NQT / 2, 64);
    fa_fwd_kernel<<<grid, 512, 0, stream>>>(Q, K, V, O);
}

// Round 8
// 112.341 us; speedup vs baseline: 1.4037x; 1.2035x over previous
//
#include <hip/hip_runtime.h>

typedef _Float16 h16;
typedef _Float16 h16x4 __attribute__((ext_vector_type(4)));
typedef _Float16 h16x8 __attribute__((ext_vector_type(8)));
typedef __fp16 fp16x2 __attribute__((ext_vector_type(2)));   // cvt_pkrtz native type
typedef float f32x4 __attribute__((ext_vector_type(4)));

#define SEQ 2048
#define RSTRIDE 8192   // b*h*d = 4*16*128
#define QTILE 256
#define NQT (SEQ / QTILE)   // 8
#define KBLK 64
#define KPAD 136       // K LDS row stride (halves)
#define VPAD 72        // Vt LDS row stride (halves)
#define DEFER_THR 8.0f

static __device__ __forceinline__ h16x8 pack8(f32x4 a, f32x4 b) {
    union { fp16x2 h2[4]; h16x8 h8; } u;
    u.h2[0] = __builtin_amdgcn_cvt_pkrtz(a[0], a[1]);
    u.h2[1] = __builtin_amdgcn_cvt_pkrtz(a[2], a[3]);
    u.h2[2] = __builtin_amdgcn_cvt_pkrtz(b[0], b[1]);
    u.h2[3] = __builtin_amdgcn_cvt_pkrtz(b[2], b[3]);
    return u.h8;
}

static __device__ __forceinline__ h16x4 pack4(float x0, float x1, float x2, float x3) {
    union { fp16x2 h2[2]; h16x4 h4; } u;
    u.h2[0] = __builtin_amdgcn_cvt_pkrtz(x0, x1);
    u.h2[1] = __builtin_amdgcn_cvt_pkrtz(x2, x3);
    return u.h4;
}

__global__ __launch_bounds__(512, 2)
void fa_fwd_kernel(const float* __restrict__ Qg, const float* __restrict__ Kg,
                   const float* __restrict__ Vg, float* __restrict__ Out)
{
    __shared__ __attribute__((aligned(16))) h16 Kl[2][KBLK * KPAD];   // [key][d]
    __shared__ __attribute__((aligned(16))) h16 Vt[2][128 * VPAD];    // [d][key^swz]

    // XCD-aware remap (256 blocks, 1/CU): XCD x owns bh in {8x..8x+7}
    const int lin = (int)blockIdx.x + 4 * (int)blockIdx.y;   // hw XCD = lin % 8
    const int bx  = (lin >> 3) & 3;               // 0..3, pairs (bx, 7-bx)
    const int bh  = 8 * (lin & 7) + (lin >> 5);   // 0..63
    const int tid  = threadIdx.x;   // 0..511 (8 waves)
    const int wave = tid >> 6;
    const int lane = tid & 63;
    const int lg   = lane >> 4;
    const int lc   = lane & 15;
    const size_t bhoff = (size_t)bh * 128;
    const float NEGINF = -__builtin_inff();
    const float SL = 0.08838834764831845f * 1.4426950408889634f;  // (1/sqrt(128))*log2(e)

    // ---- K staging geometry
    const int krow = tid >> 4;            // 0..31 (+32*it)
    const int kd0  = (tid & 15) * 8;
    const float* kbase = Kg + (size_t)krow * RSTRIDE + bhoff + kd0;
    const int kwoff = krow * KPAD + kd0;

    // ---- V staging geometry
    const int vkey0 = 4 * (tid >> 5);     // 0..60
    const int vd0   = 4 * (tid & 31);     // 0..124
    const int vcol  = vkey0 ^ (4 * (tid & 15));
    const float* vbase = Vg + (size_t)vkey0 * RSTRIDE + bhoff + vd0;

    // ---- per-lane LDS fragment bases
    const int kfoff = lc * KPAD + lg * 8;                      // + kt*16*KPAD + dk*32
    const int vfoff = lc * VPAD + ((4 * lg) ^ (4 * (lc >> 2)));// + dt*16*VPAD + 16*((2u+s)^(dt&3))

    f32x4 kra[2], krb[2], vra[4];   // prefetch registers (T14)

    for (int half = 0; half < 2; ++half) {
        const int qt = half ? (NQT - 1 - bx) : bx;
        const int q0 = qt * QTILE;
        const int wbase = q0 + wave * 32;    // wave's 32 q-rows (2 fused strips)

        // ---- Q fragments, pre-scaled
        h16x8 qf[2][4];
#pragma unroll
        for (int s2 = 0; s2 < 2; ++s2) {
            const int qrow = wbase + s2 * 16 + lc;
            const float* qp = Qg + (size_t)qrow * RSTRIDE + bhoff + lg * 8;
#pragma unroll
            for (int dk = 0; dk < 4; ++dk) {
                f32x4 a = *(const f32x4*)(qp + dk * 32);
                f32x4 b = *(const f32x4*)(qp + dk * 32 + 4);
#pragma unroll
                for (int j = 0; j < 4; ++j) { a[j] *= SL; b[j] *= SL; }
                qf[s2][dk] = pack8(a, b);
            }
        }

        f32x4 o[2][8];
#pragma unroll
        for (int s2 = 0; s2 < 2; ++s2)
#pragma unroll
            for (int dt = 0; dt < 8; ++dt) o[s2][dt] = f32x4{0.f, 0.f, 0.f, 0.f};
        float mreg[2] = {NEGINF, NEGINF};
        float lsum[2] = {0.f, 0.f};

        const int nkv = 4 * (qt + 1);

        // ---- prologue
#pragma unroll
        for (int it = 0; it < 2; ++it) {
            const float* gp = kbase + (size_t)(32 * it) * RSTRIDE;
            kra[it] = *(const f32x4*)gp;
            krb[it] = *(const f32x4*)(gp + 4);
        }
#pragma unroll
        for (int kk = 0; kk < 4; ++kk)
            vra[kk] = *(const f32x4*)(vbase + (size_t)kk * RSTRIDE);
        __syncthreads();
        {
            h16* kw = &Kl[0][kwoff];
#pragma unroll
            for (int it = 0; it < 2; ++it)
                *(h16x8*)(kw + it * 32 * KPAD) = pack8(kra[it], krb[it]);
#pragma unroll
            for (int e = 0; e < 4; ++e)
                *(h16x4*)&Vt[0][(vd0 + e) * VPAD + vcol] =
                    pack4(vra[0][e], vra[1][e], vra[2][e], vra[3][e]);
        }
        if (nkv > 1) {
            const size_t toff = (size_t)KBLK * RSTRIDE;
#pragma unroll
            for (int it = 0; it < 2; ++it) {
                const float* gp = kbase + toff + (size_t)(32 * it) * RSTRIDE;
                kra[it] = *(const f32x4*)gp;
                krb[it] = *(const f32x4*)(gp + 4);
            }
#pragma unroll
            for (int kk = 0; kk < 4; ++kk)
                vra[kk] = *(const f32x4*)(vbase + toff + (size_t)kk * RSTRIDE);
        }
        __syncthreads();

        for (int t = 0; t < nkv; ++t) {
            const int kv0 = t * KBLK;
            const int cb = t & 1;

            if (t + 1 < nkv) {
                h16* kw = &Kl[cb ^ 1][kwoff];
#pragma unroll
                for (int it = 0; it < 2; ++it)
                    *(h16x8*)(kw + it * 32 * KPAD) = pack8(kra[it], krb[it]);
#pragma unroll
                for (int e = 0; e < 4; ++e)
                    *(h16x4*)&Vt[cb ^ 1][(vd0 + e) * VPAD + vcol] =
                        pack4(vra[0][e], vra[1][e], vra[2][e], vra[3][e]);
            }
            if (t + 2 < nkv) {
                const size_t toff = (size_t)(kv0 + 2 * KBLK) * RSTRIDE;
#pragma unroll
                for (int it = 0; it < 2; ++it) {
                    const float* gp = kbase + toff + (size_t)(32 * it) * RSTRIDE;
                    kra[it] = *(const f32x4*)gp;
                    krb[it] = *(const f32x4*)(gp + 4);
                }
#pragma unroll
                for (int kk = 0; kk < 4; ++kk)
                    vra[kk] = *(const f32x4*)(vbase + toff + (size_t)kk * RSTRIDE);
            }

            // ---- fused compute: both strips share every LDS fragment load
            if (kv0 <= wbase + 31) {           // wave-uniform
                const h16* Kfb = &Kl[cb][kfoff];
                const h16* Vfb = &Vt[cb][vfoff];

                // S^T = K . Q^T for both strips: 1 load -> 2 MFMAs
                f32x4 sacc[2][4];
#pragma unroll
                for (int s2 = 0; s2 < 2; ++s2)
#pragma unroll
                    for (int kt = 0; kt < 4; ++kt) sacc[s2][kt] = f32x4{0.f, 0.f, 0.f, 0.f};
                __builtin_amdgcn_s_setprio(1);
#pragma unroll
                for (int kt = 0; kt < 4; ++kt) {
#pragma unroll
                    for (int dk = 0; dk < 4; ++dk) {
                        h16x8 a = *(const h16x8*)(Kfb + kt * 16 * KPAD + dk * 32);
                        sacc[0][kt] = __builtin_amdgcn_mfma_f32_16x16x32_f16(a, qf[0][dk], sacc[0][kt], 0, 0, 0);
                        sacc[1][kt] = __builtin_amdgcn_mfma_f32_16x16x32_f16(a, qf[1][dk], sacc[1][kt], 0, 0, 0);
                    }
                }
                __builtin_amdgcn_s_setprio(0);

                // masks + per-lane max
                float vmax[2] = {NEGINF, NEGINF};
                if (kv0 + 63 <= wbase) {       // interior for both strips
#pragma unroll
                    for (int s2 = 0; s2 < 2; ++s2)
#pragma unroll
                        for (int kt = 0; kt < 4; ++kt)
#pragma unroll
                            for (int r = 0; r < 4; ++r) vmax[s2] = fmaxf(vmax[s2], sacc[s2][kt][r]);
                } else {
#pragma unroll
                    for (int s2 = 0; s2 < 2; ++s2) {
                        const int qrow = wbase + s2 * 16 + lc;
#pragma unroll
                        for (int kt = 0; kt < 4; ++kt)
#pragma unroll
                            for (int r = 0; r < 4; ++r) {
                                const int key = kv0 + 16 * kt + 4 * lg + r;
                                float sv = (key <= qrow) ? sacc[s2][kt][r] : NEGINF;
                                sacc[s2][kt][r] = sv;
                                vmax[s2] = fmaxf(vmax[s2], sv);
                            }
                    }
                }

                // per-strip online softmax (T13 defer-max) + P fragments
                h16x8 pa[2][2];
#pragma unroll
                for (int s2 = 0; s2 < 2; ++s2) {
                    if (__any(vmax[s2] > mreg[s2] + DEFER_THR)) {
                        float rmax = fmaxf(vmax[s2], __shfl_xor(vmax[s2], 16, 64));
                        rmax = fmaxf(rmax, __shfl_xor(rmax, 32, 64));
                        const float mnew  = fmaxf(mreg[s2], rmax);
                        const float alpha = __builtin_amdgcn_exp2f(mreg[s2] - mnew);
                        mreg[s2] = mnew;
                        lsum[s2] *= alpha;
#pragma unroll
                        for (int r = 0; r < 4; ++r) {
                            const float ar = __shfl(alpha, 4 * lg + r, 64);
#pragma unroll
                            for (int dt = 0; dt < 8; ++dt) o[s2][dt][r] *= ar;
                        }
                    }
                    float psum = 0.f;
#pragma unroll
                    for (int kt = 0; kt < 4; ++kt)
#pragma unroll
                        for (int r = 0; r < 4; ++r) {
                            const float e = __builtin_amdgcn_exp2f(sacc[s2][kt][r] - mreg[s2]);
                            sacc[s2][kt][r] = e;
                            psum += e;
                        }
                    lsum[s2] += psum;
#pragma unroll
                    for (int u = 0; u < 2; ++u)
                        pa[s2][u] = pack8(sacc[s2][2 * u], sacc[s2][2 * u + 1]);
                }

                // PV for both strips: 1 fragment load -> 2 MFMAs
                __builtin_amdgcn_s_setprio(1);
#pragma unroll
                for (int dt = 0; dt < 8; ++dt) {
#pragma unroll
                    for (int u = 0; u < 2; ++u) {
                        union { h16x8 v8; h16x4 v4[2]; } bv;
                        bv.v4[0] = *(const h16x4*)(Vfb + dt * 16 * VPAD + 16 * ((2 * u + 0) ^ (dt & 3)));
                        bv.v4[1] = *(const h16x4*)(Vfb + dt * 16 * VPAD + 16 * ((2 * u + 1) ^ (dt & 3)));
                        o[0][dt] = __builtin_amdgcn_mfma_f32_16x16x32_f16(pa[0][u], bv.v8, o[0][dt], 0, 0, 0);
                        o[1][dt] = __builtin_amdgcn_mfma_f32_16x16x32_f16(pa[1][u], bv.v8, o[1][dt], 0, 0, 0);
                    }
                }
                __builtin_amdgcn_s_setprio(0);
            }
            __syncthreads();   // single barrier per tile
        } // kv tiles

        // ---- epilogue
#pragma unroll
        for (int s2 = 0; s2 < 2; ++s2) {
            float ls = lsum[s2];
            ls += __shfl_xor(ls, 16, 64);
            ls += __shfl_xor(ls, 32, 64);
#pragma unroll
            for (int r = 0; r < 4; ++r) {
                const float lr  = __shfl(ls, 4 * lg + r, 64);
                const float inv = 1.0f / lr;
                const int qrow  = wbase + s2 * 16 + 4 * lg + r;
                float* op = Out + (size_t)qrow * RSTRIDE + bhoff + lc;
#pragma unroll
                for (int dt = 0; dt < 8; ++dt) op[dt * 16] = o[s2][dt][r] * inv;
            }
        }
    } // half
}

extern "C" void kernel_launch(void* const* d_in, const int* in_sizes, int n_in,
                              void* d_out, int out_size, void* d_ws, size_t ws_size,
                              hipStream_t stream) {
    (void)in_sizes; (void)n_in; (void)out_size; (void)d_ws; (void)ws_size;
    const float* Q = (const float*)d_in[0];
    const float* K = (const float*)d_in[1];
    const float* V = (const float*)d_in[2];
    float* O = (float*)d_out;
    dim3 grid(NQT / 2, 64);
    fa_fwd_kernel<<<grid, 512, 0, stream>>>(Q, K, V, O);
}